// Round 3
// baseline (324.000 us; speedup 1.0000x reference)
//
#include <hip/hip_runtime.h>
#include <math.h>

// B=8192, T=1024, WS=5, H=6, IN=15, OUT=2
#define TLEN  1024
#define NSTEP 1019

// DPP sum over each consecutive 8-lane group (result in all 8 lanes).
template <int CTRL>
__device__ __forceinline__ float dpp_add(float v) {
    union { int i; float f; } in, out;
    in.f = v;
    out.i = __builtin_amdgcn_update_dpp(0, in.i, CTRL, 0xF, 0xF, false);
    return v + out.f;
}
__device__ __forceinline__ float sum8(float v) {
    v = dpp_add<0xB1>(v);    // quad_perm xor1
    v = dpp_add<0x4E>(v);    // quad_perm xor2
    v = dpp_add<0x141>(v);   // row_half_mirror = xor4
    return v;
}
// 4 independent 8-lane reductions, round-interleaved so the VALU->DPP hazard
// wait-states of one stream are filled by the others' issue. Bit-identical
// per value to sum8().
__device__ __forceinline__ void sum8x4(float& a, float& b, float& c, float& d) {
    a = dpp_add<0xB1>(a);  b = dpp_add<0xB1>(b);  c = dpp_add<0xB1>(c);  d = dpp_add<0xB1>(d);
    a = dpp_add<0x4E>(a);  b = dpp_add<0x4E>(b);  c = dpp_add<0x4E>(c);  d = dpp_add<0x4E>(d);
    a = dpp_add<0x141>(a); b = dpp_add<0x141>(b); c = dpp_add<0x141>(c); d = dpp_add<0x141>(d);
}

__device__ __forceinline__ float fast_exp2(float z) {
#if __has_builtin(__builtin_amdgcn_exp2f)
    return __builtin_amdgcn_exp2f(z);
#else
    return exp2f(z);
#endif
}

__global__ __launch_bounds__(64) void MLP_or_nextstep_kernel(
    const float* __restrict__ traj,   // (B, T, 3)
    const float* __restrict__ W1,     // (6, 15)
    const float* __restrict__ b1,     // (6,)
    const float* __restrict__ W2,     // (2, 6)
    const float* __restrict__ b2,     // (2,)
    float* __restrict__ out)          // (B, 1019, 2)
{
    __shared__ float lds_u[TLEN][16]; // 64 KB: u for the block's 16 elements, all T

    const int lane = threadIdx.x;
    const int g    = lane >> 3;        // element slot within a set (8 per set)
    const int n    = lane & 7;         // neuron id (0..5 real; 6,7 carry biases)
    const int bstart = blockIdx.x * 16;
    const int bX = bstart + g;         // set X element
    const int bY = bstart + 8 + g;     // set Y element

    const float* __restrict__ baseX = traj + (size_t)bX * (TLEN * 3);
    const float* __restrict__ baseY = traj + (size_t)bY * (TLEN * 3);
    float2* outbX = (float2*)out + (size_t)bX * NSTEP;
    float2* outbY = (float2*)out + (size_t)bY * NSTEP;
    const bool is_store_lane = (n == 0);

    // ---- stage ALL u rows: lane i -> elem (i&15), row 4j+(i>>4); dest word 64j+i ----
    {
        const int s_elem = lane & 15;
        const int s_row  = lane >> 4;
        const float* __restrict__ sbase = traj + (size_t)(bstart + s_elem) * (TLEN * 3);
        for (int j = 0; j < TLEN / 4; ++j) {
            const float* gp = sbase + (size_t)(4 * j + s_row) * 3;
            __builtin_amdgcn_global_load_lds(
                (const __attribute__((address_space(1))) void*)gp,
                (__attribute__((address_space(3))) void*)&lds_u[4 * j][0],
                4, 0, 0);
        }
    }

    // ---- per-lane weights, fully folded ----
    const float KK = 2.8853900817779268f;   // 2*log2(e)
    const int nr = (n < 6) ? n : 5;
    float w1row[15], b1r;
#pragma unroll
    for (int j = 0; j < 15; ++j) w1row[j] = KK * W1[nr * 15 + j];
    b1r = KK * b1[nr];
    const float w2a_l = (n < 6) ? W2[n]     : 0.0f;
    const float w2b_l = (n < 6) ? W2[6 + n] : 0.0f;
    const float bias_a = (n == 6) ? b2[0] : 0.0f;
    const float bias_b = (n == 7) ? b2[1] : 0.0f;
    const float c1a = -2.0f * w2a_l, c0a = w2a_l + bias_a;
    const float c1b = -2.0f * w2b_l, c0b = w2b_l + bias_b;

    auto mlp = [&](const float* __restrict__ x, float& ya, float& yb) {
        float z0 = w1row[0] * x[0];
        float z1 = w1row[5] * x[5];
        float z2 = fmaf(w1row[10], x[10], b1r);
#pragma unroll
        for (int j = 1; j < 5; ++j) {
            z0 = fmaf(w1row[j],      x[j],      z0);
            z1 = fmaf(w1row[5 + j],  x[5 + j],  z1);
            z2 = fmaf(w1row[10 + j], x[10 + j], z2);
        }
        float z = (z0 + z1) + z2;
        float r = __builtin_amdgcn_rcpf(fast_exp2(z) + 1.0f);
        ya = sum8(fmaf(c1a, r, c0a));
        yb = sum8(fmaf(c1b, r, c0b));
    };

    // ---- warmup (one-time; latency-irrelevant) ----
    float paX[5], pbX[5], paY[5], pbY[5];

#define WARMUP(SFX)                                                              \
    {                                                                            \
        float uu[12], vv[5], wc[5];                                              \
        _Pragma("unroll")                                                        \
        for (int i = 0; i < 12; ++i) uu[i] = base##SFX[i * 3];                   \
        _Pragma("unroll")                                                        \
        for (int i = 0; i < 5; ++i) { vv[i] = base##SFX[i * 3 + 1];              \
                                      wc[i] = base##SFX[i * 3 + 2]; }            \
        {                                                                        \
            float x[15] = {uu[0],uu[1],uu[2],uu[3],uu[4],                        \
                           vv[0],vv[1],vv[2],vv[3],vv[4],                        \
                           wc[0],wc[1],wc[2],wc[3],wc[4]};                       \
            mlp(x, pa##SFX[0], pb##SFX[0]);                                      \
        }                                                                        \
        {                                                                        \
            float x[15] = {uu[1],uu[2],uu[3],uu[4],uu[5],                        \
                           vv[1],vv[2],vv[3],vv[4],pa##SFX[0],                   \
                           wc[1],wc[2],wc[3],wc[4],pb##SFX[0]};                  \
            mlp(x, pa##SFX[1], pb##SFX[1]);                                      \
        }                                                                        \
        {                                                                        \
            float x[15] = {uu[2],uu[3],uu[4],uu[6],uu[7],                        \
                           vv[2],vv[3],vv[4],pa##SFX[0],pa##SFX[1],              \
                           wc[2],wc[3],wc[4],pb##SFX[0],pb##SFX[1]};             \
            mlp(x, pa##SFX[2], pb##SFX[2]);                                      \
        }                                                                        \
        {                                                                        \
            float x[15] = {uu[3],uu[4],uu[7],uu[8],uu[9],                        \
                           vv[3],vv[4],pa##SFX[0],pa##SFX[1],pa##SFX[2],         \
                           wc[3],wc[4],pb##SFX[0],pb##SFX[1],pb##SFX[2]};        \
            mlp(x, pa##SFX[3], pb##SFX[3]);                                      \
        }                                                                        \
        {                                                                        \
            float x[15] = {uu[4],uu[8],uu[9],uu[10],uu[11],                      \
                           vv[4],pa##SFX[0],pa##SFX[1],pa##SFX[2],pa##SFX[3],    \
                           wc[4],pb##SFX[0],pb##SFX[1],pb##SFX[2],pb##SFX[3]};   \
            mlp(x, pa##SFX[4], pb##SFX[4]);                                      \
        }                                                                        \
        if (is_store_lane) {                                                     \
            _Pragma("unroll")                                                    \
            for (int i = 0; i < 5; ++i)                                          \
                outb##SFX[i] = make_float2(pa##SFX[i], pb##SFX[i]);              \
        }                                                                        \
    }

    WARMUP(X)
    WARMUP(Y)
#undef WARMUP

    __syncthreads();   // staging drain, once

    // ---- scan t = 5..1018, two independent element sets interleaved ----
    float awX[5], bwX[5], awY[5], bwY[5];
#pragma unroll
    for (int i = 0; i < 5; ++i) { awX[i] = paX[i]; bwX[i] = pbX[i];
                                  awY[i] = paY[i]; bwY[i] = pbY[i]; }

    const float* upX = &lds_u[5][g];       // u[t0+i] = upX[16*i]
    const float* upY = &lds_u[5][8 + g];
    float2* spX = outbX + n + 5;           // lane n stores step-slot n of each 8-block
    float2* spY = outbY + n + 5;
    float unAX[9], unBX[9], unAY[9], unBY[9];

    // preload first group (t0=5)
#pragma unroll
    for (int i = 0; i < 9; ++i) { unAX[i] = upX[16 * i]; unAY[i] = upY[16 * i]; }
    const float* upnX = upX + 80;          // next group: t0=10
    const float* upnY = upY + 80;

#define LOADN2(UB)                                                           \
    {                                                                        \
        _Pragma("unroll")                                                    \
        for (int i = 0; i < 9; ++i) { un##UB##X[i] = upnX[16 * i];           \
                                      un##UB##Y[i] = upnY[16 * i]; }         \
        upnX += 80; upnY += 80;                                              \
    }

    // du[i] = z0 chain for step i of a group (identical fma order)
    float duCX[5], duDX[5], duCY[5], duDY[5];
#pragma unroll
    for (int i = 0; i < 5; ++i) {
        float dX = w1row[0] * unAX[i];
        float dY = w1row[0] * unAY[i];
        dX = fmaf(w1row[1], unAX[i + 1], dX);
        dY = fmaf(w1row[1], unAY[i + 1], dY);
        dX = fmaf(w1row[2], unAX[i + 2], dX);
        dY = fmaf(w1row[2], unAY[i + 2], dY);
        dX = fmaf(w1row[3], unAX[i + 3], dX);
        dY = fmaf(w1row[3], unAY[i + 3], dY);
        dX = fmaf(w1row[4], unAX[i + 4], dX);
        dY = fmaf(w1row[4], unAY[i + 4], dY);
        duCX[i] = dX;
        duCY[i] = dY;
    }

    LOADN2(B)                              // t0=10; upn -> 15

    // partials for first step (t=5, S=0): first 4 terms of z1/z2, identical order
    float pAcX, pBcX, pAnX, pBnX, pAcY, pBcY, pAnY, pBnY;
    pAcX = w1row[5] * awX[0];
    pAcY = w1row[5] * awY[0];
    pAcX = fmaf(w1row[6], awX[1], pAcX);
    pAcY = fmaf(w1row[6], awY[1], pAcY);
    pAcX = fmaf(w1row[7], awX[2], pAcX);
    pAcY = fmaf(w1row[7], awY[2], pAcY);
    pAcX = fmaf(w1row[8], awX[3], pAcX);
    pAcY = fmaf(w1row[8], awY[3], pAcY);
    pBcX = fmaf(w1row[10], bwX[0], b1r);
    pBcY = fmaf(w1row[10], bwY[0], b1r);
    pBcX = fmaf(w1row[11], bwX[1], pBcX);
    pBcY = fmaf(w1row[11], bwY[1], pBcY);
    pBcX = fmaf(w1row[12], bwX[2], pBcX);
    pBcY = fmaf(w1row[12], bwY[2], pBcY);
    pBcX = fmaf(w1row[13], bwX[3], pBcX);
    pBcY = fmaf(w1row[13], bwY[3], pBcY);

// STEP2: one recurrence step for BOTH sets, hand-interleaved so each set's
// chain stalls are covered by the other's issue. Per-element FP ops and
// ordering identical to the R1 kernel (bit-exact).
#define STEP2(S, DC, DN, UB, J, M)                                           \
    {                                                                        \
        float tAX = fmaf(w1row[9],  awX[((S) + 4) % 5], pAcX);               \
        float tAY = fmaf(w1row[9],  awY[((S) + 4) % 5], pAcY);               \
        float tBX = fmaf(w1row[14], bwX[((S) + 4) % 5], pBcX);               \
        float tBY = fmaf(w1row[14], bwY[((S) + 4) % 5], pBcY);               \
        float zX  = (du##DC##X[S] + tAX) + tBX;                              \
        float zY  = (du##DC##Y[S] + tAY) + tBY;                              \
        float exX = fast_exp2(zX);                                           \
        float exY = fast_exp2(zY);                                           \
        pAnX = w1row[5] * awX[((S) + 1) % 5];                                \
        pAnY = w1row[5] * awY[((S) + 1) % 5];                                \
        pAnX = fmaf(w1row[6], awX[((S) + 2) % 5], pAnX);                     \
        pAnY = fmaf(w1row[6], awY[((S) + 2) % 5], pAnY);                     \
        pAnX = fmaf(w1row[7], awX[((S) + 3) % 5], pAnX);                     \
        pAnY = fmaf(w1row[7], awY[((S) + 3) % 5], pAnY);                     \
        pAnX = fmaf(w1row[8], awX[((S) + 4) % 5], pAnX);                     \
        pAnY = fmaf(w1row[8], awY[((S) + 4) % 5], pAnY);                     \
        pBnX = fmaf(w1row[10], bwX[((S) + 1) % 5], b1r);                     \
        pBnY = fmaf(w1row[10], bwY[((S) + 1) % 5], b1r);                     \
        pBnX = fmaf(w1row[11], bwX[((S) + 2) % 5], pBnX);                    \
        pBnY = fmaf(w1row[11], bwY[((S) + 2) % 5], pBnY);                    \
        pBnX = fmaf(w1row[12], bwX[((S) + 3) % 5], pBnX);                    \
        pBnY = fmaf(w1row[12], bwY[((S) + 3) % 5], pBnY);                    \
        pBnX = fmaf(w1row[13], bwX[((S) + 4) % 5], pBnX);                    \
        pBnY = fmaf(w1row[13], bwY[((S) + 4) % 5], pBnY);                    \
        {                                                                    \
            float dX = w1row[0] * un##UB##X[S];                              \
            float dY = w1row[0] * un##UB##Y[S];                              \
            dX = fmaf(w1row[1], un##UB##X[(S) + 1], dX);                     \
            dY = fmaf(w1row[1], un##UB##Y[(S) + 1], dY);                     \
            dX = fmaf(w1row[2], un##UB##X[(S) + 2], dX);                     \
            dY = fmaf(w1row[2], un##UB##Y[(S) + 2], dY);                     \
            dX = fmaf(w1row[3], un##UB##X[(S) + 3], dX);                     \
            dY = fmaf(w1row[3], un##UB##Y[(S) + 3], dY);                     \
            dX = fmaf(w1row[4], un##UB##X[(S) + 4], dX);                     \
            dY = fmaf(w1row[4], un##UB##Y[(S) + 4], dY);                     \
            du##DN##X[S] = dX;                                               \
            du##DN##Y[S] = dY;                                               \
        }                                                                    \
        float rX = __builtin_amdgcn_rcpf(exX + 1.0f);                        \
        float rY = __builtin_amdgcn_rcpf(exY + 1.0f);                        \
        float vaX = fmaf(c1a, rX, c0a);                                      \
        float vbX = fmaf(c1b, rX, c0b);                                      \
        float vaY = fmaf(c1a, rY, c0a);                                      \
        float vbY = fmaf(c1b, rY, c0b);                                      \
        sum8x4(vaX, vbX, vaY, vbY);                                          \
        if (n == (J)) { kaX##M = vaX; kbX##M = vbX;                          \
                        kaY##M = vaY; kbY##M = vbY; }                        \
        awX[(S) % 5] = vaX; bwX[(S) % 5] = vbX;                              \
        awY[(S) % 5] = vaY; bwY[(S) % 5] = vbY;                              \
        pAcX = pAnX; pBcX = pBnX; pAcY = pAnY; pBcY = pBnY;                  \
    }

#define STORE2(M)                                                            \
    {                                                                        \
        spX[8 * (M)] = make_float2(kaX##M, kbX##M);                          \
        spY[8 * (M)] = make_float2(kaY##M, kbY##M);                          \
    }

    // 25 superblocks x 40 steps: t = 5 .. 1004
    for (int sb = 0; sb < 25; ++sb) {
        float kaX0 = 0, kbX0 = 0, kaX1 = 0, kbX1 = 0, kaX2 = 0, kbX2 = 0,
              kaX3 = 0, kbX3 = 0, kaX4 = 0, kbX4 = 0;
        float kaY0 = 0, kbY0 = 0, kaY1 = 0, kbY1 = 0, kaY2 = 0, kbY2 = 0,
              kaY3 = 0, kbY3 = 0, kaY4 = 0, kbY4 = 0;
        // gg0
        LOADN2(A)
        STEP2(0, C, D, B, 0, 0) STEP2(1, C, D, B, 1, 0) STEP2(2, C, D, B, 2, 0)
        STEP2(3, C, D, B, 3, 0) STEP2(4, C, D, B, 4, 0)
        // gg1
        LOADN2(B)
        STEP2(0, D, C, A, 5, 0) STEP2(1, D, C, A, 6, 0) STEP2(2, D, C, A, 7, 0) STORE2(0)
        STEP2(3, D, C, A, 0, 1) STEP2(4, D, C, A, 1, 1)
        // gg2
        LOADN2(A)
        STEP2(0, C, D, B, 2, 1) STEP2(1, C, D, B, 3, 1) STEP2(2, C, D, B, 4, 1)
        STEP2(3, C, D, B, 5, 1) STEP2(4, C, D, B, 6, 1)
        // gg3
        LOADN2(B)
        STEP2(0, D, C, A, 7, 1) STORE2(1)
        STEP2(1, D, C, A, 0, 2) STEP2(2, D, C, A, 1, 2) STEP2(3, D, C, A, 2, 2) STEP2(4, D, C, A, 3, 2)
        // gg4
        LOADN2(A)
        STEP2(0, C, D, B, 4, 2) STEP2(1, C, D, B, 5, 2) STEP2(2, C, D, B, 6, 2)
        STEP2(3, C, D, B, 7, 2) STORE2(2)
        STEP2(4, C, D, B, 0, 3)
        // gg5
        LOADN2(B)
        STEP2(0, D, C, A, 1, 3) STEP2(1, D, C, A, 2, 3) STEP2(2, D, C, A, 3, 3)
        STEP2(3, D, C, A, 4, 3) STEP2(4, D, C, A, 5, 3)
        // gg6
        LOADN2(A)
        STEP2(0, C, D, B, 6, 3) STEP2(1, C, D, B, 7, 3) STORE2(3)
        STEP2(2, C, D, B, 0, 4) STEP2(3, C, D, B, 1, 4) STEP2(4, C, D, B, 2, 4)
        // gg7
        LOADN2(B)
        STEP2(0, D, C, A, 3, 4) STEP2(1, D, C, A, 4, 4) STEP2(2, D, C, A, 5, 4)
        STEP2(3, D, C, A, 6, 4) STEP2(4, D, C, A, 7, 4) STORE2(4)

        spX += 40; spY += 40;
    }

    // ---- tail: t = 1005..1018 (14 steps), per-step stores from lane n==0 ----
    // state: unA* hold rows 1005..1013, unB* hold 1010..1018, upn* -> 1015
    float2* tpX = outbX + 1005;
    float2* tpY = outbY + 1005;
#define TSTEP2(S, UB, K)                                                     \
    {                                                                        \
        float z0X = w1row[0] * un##UB##X[S];                                 \
        float z0Y = w1row[0] * un##UB##Y[S];                                 \
        float z1X = w1row[5] * awX[(S) % 5];                                 \
        float z1Y = w1row[5] * awY[(S) % 5];                                 \
        float z2X = fmaf(w1row[10], bwX[(S) % 5], b1r);                      \
        float z2Y = fmaf(w1row[10], bwY[(S) % 5], b1r);                      \
        z0X = fmaf(w1row[1], un##UB##X[(S) + 1], z0X);                       \
        z0Y = fmaf(w1row[1], un##UB##Y[(S) + 1], z0Y);                       \
        z1X = fmaf(w1row[6], awX[((S) + 1) % 5], z1X);                       \
        z1Y = fmaf(w1row[6], awY[((S) + 1) % 5], z1Y);                       \
        z2X = fmaf(w1row[11], bwX[((S) + 1) % 5], z2X);                      \
        z2Y = fmaf(w1row[11], bwY[((S) + 1) % 5], z2Y);                      \
        z0X = fmaf(w1row[2], un##UB##X[(S) + 2], z0X);                       \
        z0Y = fmaf(w1row[2], un##UB##Y[(S) + 2], z0Y);                       \
        z1X = fmaf(w1row[7], awX[((S) + 2) % 5], z1X);                       \
        z1Y = fmaf(w1row[7], awY[((S) + 2) % 5], z1Y);                       \
        z2X = fmaf(w1row[12], bwX[((S) + 2) % 5], z2X);                      \
        z2Y = fmaf(w1row[12], bwY[((S) + 2) % 5], z2Y);                      \
        z0X = fmaf(w1row[3], un##UB##X[(S) + 3], z0X);                       \
        z0Y = fmaf(w1row[3], un##UB##Y[(S) + 3], z0Y);                       \
        z1X = fmaf(w1row[8], awX[((S) + 3) % 5], z1X);                       \
        z1Y = fmaf(w1row[8], awY[((S) + 3) % 5], z1Y);                       \
        z2X = fmaf(w1row[13], bwX[((S) + 3) % 5], z2X);                      \
        z2Y = fmaf(w1row[13], bwY[((S) + 3) % 5], z2Y);                      \
        z0X = fmaf(w1row[4], un##UB##X[(S) + 4], z0X);                       \
        z0Y = fmaf(w1row[4], un##UB##Y[(S) + 4], z0Y);                       \
        z1X = fmaf(w1row[9], awX[((S) + 4) % 5], z1X);                       \
        z1Y = fmaf(w1row[9], awY[((S) + 4) % 5], z1Y);                       \
        z2X = fmaf(w1row[14], bwX[((S) + 4) % 5], z2X);                      \
        z2Y = fmaf(w1row[14], bwY[((S) + 4) % 5], z2Y);                      \
        float zX = (z0X + z1X) + z2X;                                        \
        float zY = (z0Y + z1Y) + z2Y;                                        \
        float rX = __builtin_amdgcn_rcpf(fast_exp2(zX) + 1.0f);              \
        float rY = __builtin_amdgcn_rcpf(fast_exp2(zY) + 1.0f);              \
        float vaX = fmaf(c1a, rX, c0a);                                      \
        float vbX = fmaf(c1b, rX, c0b);                                      \
        float vaY = fmaf(c1a, rY, c0a);                                      \
        float vbY = fmaf(c1b, rY, c0b);                                      \
        sum8x4(vaX, vbX, vaY, vbY);                                          \
        if (is_store_lane) { tpX[K] = make_float2(vaX, vbX);                 \
                             tpY[K] = make_float2(vaY, vbY); }               \
        awX[(S) % 5] = vaX; bwX[(S) % 5] = vbX;                              \
        awY[(S) % 5] = vaY; bwY[(S) % 5] = vbY;                              \
    }

    TSTEP2(0, A, 0) TSTEP2(1, A, 1) TSTEP2(2, A, 2) TSTEP2(3, A, 3) TSTEP2(4, A, 4)
    LOADN2(A)   // t0=1015, rows 1015..1023 (in bounds)
    TSTEP2(0, B, 5) TSTEP2(1, B, 6) TSTEP2(2, B, 7) TSTEP2(3, B, 8) TSTEP2(4, B, 9)
    TSTEP2(0, A, 10) TSTEP2(1, A, 11) TSTEP2(2, A, 12) TSTEP2(3, A, 13)

#undef TSTEP2
#undef STORE2
#undef STEP2
#undef LOADN2
}

extern "C" void kernel_launch(void* const* d_in, const int* in_sizes, int n_in,
                              void* d_out, int out_size, void* d_ws, size_t ws_size,
                              hipStream_t stream) {
    const float* traj = (const float*)d_in[0];
    const float* W1   = (const float*)d_in[1];
    const float* b1   = (const float*)d_in[2];
    const float* W2   = (const float*)d_in[3];
    const float* b2   = (const float*)d_in[4];
    float* out = (float*)d_out;

    // 8 lanes/element, 16 elements/wave (2 independent sets) -> 512 single-wave blocks
    const int grid = 8192 / 16;
    MLP_or_nextstep_kernel<<<grid, 64, 0, stream>>>(traj, W1, b1, W2, b2, out);
}

// Round 4
// 237.196 us; speedup vs baseline: 1.3660x; 1.3660x over previous
//
#include <hip/hip_runtime.h>
#include <math.h>

// B=8192, T=1024, WS=5, H=6, IN=15, OUT=2
#define TLEN  1024
#define NSTEP 1019

// DPP sum over each consecutive 8-lane group (result in all 8 lanes).
template <int CTRL>
__device__ __forceinline__ float dpp_add(float v) {
    union { int i; float f; } in, out;
    in.f = v;
    out.i = __builtin_amdgcn_update_dpp(0, in.i, CTRL, 0xF, 0xF, false);
    return v + out.f;
}
__device__ __forceinline__ float sum8(float v) {
    v = dpp_add<0xB1>(v);    // quad_perm xor1
    v = dpp_add<0x4E>(v);    // quad_perm xor2
    v = dpp_add<0x141>(v);   // row_half_mirror = xor4
    return v;
}
// cross-half combine: v + (other 8-lane half of the 16-lane row), row_ror:8
__device__ __forceinline__ float comb16(float v) {
    return dpp_add<0x128>(v);
}

__device__ __forceinline__ float fast_exp2(float z) {
#if __has_builtin(__builtin_amdgcn_exp2f)
    return __builtin_amdgcn_exp2f(z);
#else
    return exp2f(z);
#endif
}

__global__ __launch_bounds__(64) void MLP_or_nextstep_kernel(
    const float* __restrict__ traj,   // (B, T, 3)
    const float* __restrict__ W1,     // (6, 15)
    const float* __restrict__ b1,     // (6,)
    const float* __restrict__ W2,     // (2, 6)
    const float* __restrict__ b2,     // (2,)
    float* __restrict__ out)          // (B, 1019, 2)
{
    __shared__ float lds_u[TLEN][4];  // 16 KB: u for the block's 4 elements, all T

    const int lane = threadIdx.x;
    const int e    = lane >> 4;        // element slot (4 per wave, 16 lanes each)
    const int kk   = (lane >> 3) & 1;  // half: 0 -> {z0,z1}/a-output, 1 -> {z2}/b-output
    const int n    = lane & 7;         // neuron id (0..5 real; 6 carries bias)
    const int bstart = blockIdx.x * 4;
    const int b = bstart + e;

    const float* __restrict__ base = traj + (size_t)b * (TLEN * 3);
    float* outf = out + (size_t)b * (NSTEP * 2);

    // ---- stage ALL u rows: lane i -> elem (i&3), row 16j+(i>>2); dest word 64j+i ----
    {
        const int s_elem = lane & 3;
        const int s_row  = lane >> 2;
        const float* __restrict__ sbase = traj + (size_t)(bstart + s_elem) * (TLEN * 3);
        for (int j = 0; j < TLEN / 16; ++j) {
            const float* gp = sbase + (size_t)(16 * j + s_row) * 3;
            __builtin_amdgcn_global_load_lds(
                (const __attribute__((address_space(1))) void*)gp,
                (__attribute__((address_space(3))) void*)&lds_u[16 * j][0],
                4, 0, 0);
        }
    }

    // ---- per-lane weights, split-K folded ----
    // z = (2*log2e)*preact ; tanh = 1 - 2/(2^z+1) = 1 - 2*r
    // k=0 lane computes z0 (u-dot) + z1 (a-hist dot); k=1 computes z2 (b-hist dot + b1).
    // z = zp + dpp_ror8(zp) == (z0+z1)+z2 (k=0) / z2+(z0+z1) (k=1) -- commutative, bit-same.
    const float KK = 2.8853900817779268f;   // 2*log2(e)
    const int nr = (n < 6) ? n : 5;
    float w1row[15];
#pragma unroll
    for (int j = 0; j < 15; ++j) w1row[j] = KK * W1[nr * 15 + j];
    const float b1r = KK * b1[nr];
    float wu[5], wh[5];
#pragma unroll
    for (int j = 0; j < 5; ++j) {
        wu[j] = kk ? 0.0f : w1row[j];          // u-dot weights (k=0 only)
        wh[j] = kk ? w1row[10 + j] : w1row[5 + j];  // own-half history weights
    }
    const float seed = kk ? b1r : 0.0f;        // z2 starts at b1r; z1 starts at 0
    const float w2_l = (n < 6) ? W2[kk * 6 + n] : 0.0f;
    const float bias = (n == 6) ? b2[kk] : 0.0f;
    const float c1 = -2.0f * w2_l, c0 = w2_l + bias;

    // ---- warmup (one-time; latency-irrelevant) ----
    // h[] = own-half sliding window: starts as v (k=0) / w (k=1) raw inputs,
    // pushes own-half outputs. Identical summand sets & order to reference.
    float h[5];
    float uu[12];
#pragma unroll
    for (int i = 0; i < 12; ++i) uu[i] = base[i * 3];
#pragma unroll
    for (int i = 0; i < 5; ++i) h[i] = base[i * 3 + 1 + kk];

    auto wstep = [&](float x0, float x1, float x2, float x3, float x4) -> float {
        float zh = fmaf(wh[0], h[0], seed);
        zh = fmaf(wh[1], h[1], zh);
        zh = fmaf(wh[2], h[2], zh);
        zh = fmaf(wh[3], h[3], zh);
        zh = fmaf(wh[4], h[4], zh);
        float du = wu[0] * x0;
        du = fmaf(wu[1], x1, du);
        du = fmaf(wu[2], x2, du);
        du = fmaf(wu[3], x3, du);
        du = fmaf(wu[4], x4, du);
        float zp = du + zh;
        float z  = comb16(zp);
        float r  = __builtin_amdgcn_rcpf(fast_exp2(z) + 1.0f);
        float y  = sum8(fmaf(c1, r, c0));
        h[0] = h[1]; h[1] = h[2]; h[2] = h[3]; h[3] = h[4]; h[4] = y;
        return y;
    };

    {
        float pv[5];
        pv[0] = wstep(uu[0], uu[1], uu[2], uu[3], uu[4]);
        pv[1] = wstep(uu[1], uu[2], uu[3], uu[4], uu[5]);
        pv[2] = wstep(uu[2], uu[3], uu[4], uu[6], uu[7]);
        pv[3] = wstep(uu[3], uu[4], uu[7], uu[8], uu[9]);
        pv[4] = wstep(uu[4], uu[8], uu[9], uu[10], uu[11]);
        if (n == 0) {
#pragma unroll
            for (int i = 0; i < 5; ++i) outf[2 * i + kk] = pv[i];
        }
    }

    __syncthreads();   // staging drain, once

    // ---- scan t = 5..1018, software-pipelined, 2 waves/SIMD chip-wide ----
    // h[] now holds {pv0..pv4} (own half).
    const float* up  = &lds_u[5][e];   // u[t0+i] = up[4*i]
    const float* upn;
    float* spf = outf + (n + 5) * 2 + kk;  // lane n stores step-slot n, own component
    float unA[9], unB[9];

#pragma unroll
    for (int i = 0; i < 9; ++i) unA[i] = up[4 * i];
    upn = up + 20;                     // next group to load: t0=10

#define LOADN(BUF)                                                           \
    {                                                                        \
        _Pragma("unroll")                                                    \
        for (int i = 0; i < 9; ++i) BUF[i] = upn[4 * i];                     \
        upn += 20;                                                           \
    }

    // du[i] = z0 chain for step i of a group (k=0 real; k=1 -> +-0, unused)
    float duC[5], duD[5];
#pragma unroll
    for (int i = 0; i < 5; ++i) {
        float d = wu[0] * unA[i];
        d = fmaf(wu[1], unA[i + 1], d);
        d = fmaf(wu[2], unA[i + 2], d);
        d = fmaf(wu[3], unA[i + 3], d);
        d = fmaf(wu[4], unA[i + 4], d);
        duC[i] = d;
    }

    LOADN(unB)                         // t0=10; upn -> 15

    // partial for first step (t=5, S=0): history terms at positions 0..3
    float pC, pN;
    pC = fmaf(wh[0], h[0], seed);
    pC = fmaf(wh[1], h[1], pC);
    pC = fmaf(wh[2], h[2], pC);
    pC = fmaf(wh[3], h[3], pC);

// STEP: finish step S (chain: fma -> add -> comb-dpp -> exp -> add -> rcp ->
// fma -> 3 dpp). Next-step partial + next-group du sit in the exp shadow;
// the co-resident second wave on each SIMD fills the remaining stalls.
#define STEP(S, DUC, DUN, UN, J, M)                                          \
    {                                                                        \
        float t_  = fmaf(wh[4], h[((S) + 4) % 5], pC);                       \
        float zp_ = DUC[S] + t_;                                             \
        float z_  = comb16(zp_);                                             \
        float ex_ = fast_exp2(z_);                                           \
        pN = fmaf(wh[0], h[((S) + 1) % 5], seed);                            \
        pN = fmaf(wh[1], h[((S) + 2) % 5], pN);                              \
        pN = fmaf(wh[2], h[((S) + 3) % 5], pN);                              \
        pN = fmaf(wh[3], h[((S) + 4) % 5], pN);                              \
        {                                                                    \
            float d_ = wu[0] * UN[S];                                        \
            d_ = fmaf(wu[1], UN[(S) + 1], d_);                               \
            d_ = fmaf(wu[2], UN[(S) + 2], d_);                               \
            d_ = fmaf(wu[3], UN[(S) + 3], d_);                               \
            d_ = fmaf(wu[4], UN[(S) + 4], d_);                               \
            DUN[S] = d_;                                                     \
        }                                                                    \
        float r_ = __builtin_amdgcn_rcpf(ex_ + 1.0f);                        \
        float y_ = fmaf(c1, r_, c0);                                         \
        y_ = dpp_add<0xB1>(y_);                                              \
        y_ = dpp_add<0x4E>(y_);                                              \
        y_ = dpp_add<0x141>(y_);                                             \
        if (n == (J)) ks##M = y_;                                            \
        h[(S) % 5] = y_;                                                     \
        pC = pN;                                                             \
    }

#define STORE(M) spf[16 * (M)] = ks##M;

    // 25 superblocks x 40 steps: t = 5 .. 1004
    for (int sb = 0; sb < 25; ++sb) {
        float ks0 = 0, ks1 = 0, ks2 = 0, ks3 = 0, ks4 = 0;
        // gg0: compute group A-data (duC), build duD from unB, refill unA
        LOADN(unA)
        STEP(0, duC, duD, unB, 0, 0) STEP(1, duC, duD, unB, 1, 0) STEP(2, duC, duD, unB, 2, 0)
        STEP(3, duC, duD, unB, 3, 0) STEP(4, duC, duD, unB, 4, 0)
        // gg1
        LOADN(unB)
        STEP(0, duD, duC, unA, 5, 0) STEP(1, duD, duC, unA, 6, 0) STEP(2, duD, duC, unA, 7, 0) STORE(0)
        STEP(3, duD, duC, unA, 0, 1) STEP(4, duD, duC, unA, 1, 1)
        // gg2
        LOADN(unA)
        STEP(0, duC, duD, unB, 2, 1) STEP(1, duC, duD, unB, 3, 1) STEP(2, duC, duD, unB, 4, 1)
        STEP(3, duC, duD, unB, 5, 1) STEP(4, duC, duD, unB, 6, 1)
        // gg3
        LOADN(unB)
        STEP(0, duD, duC, unA, 7, 1) STORE(1)
        STEP(1, duD, duC, unA, 0, 2) STEP(2, duD, duC, unA, 1, 2) STEP(3, duD, duC, unA, 2, 2) STEP(4, duD, duC, unA, 3, 2)
        // gg4
        LOADN(unA)
        STEP(0, duC, duD, unB, 4, 2) STEP(1, duC, duD, unB, 5, 2) STEP(2, duC, duD, unB, 6, 2)
        STEP(3, duC, duD, unB, 7, 2) STORE(2)
        STEP(4, duC, duD, unB, 0, 3)
        // gg5
        LOADN(unB)
        STEP(0, duD, duC, unA, 1, 3) STEP(1, duD, duC, unA, 2, 3) STEP(2, duD, duC, unA, 3, 3)
        STEP(3, duD, duC, unA, 4, 3) STEP(4, duD, duC, unA, 5, 3)
        // gg6
        LOADN(unA)
        STEP(0, duC, duD, unB, 6, 3) STEP(1, duC, duD, unB, 7, 3) STORE(3)
        STEP(2, duC, duD, unB, 0, 4) STEP(3, duC, duD, unB, 1, 4) STEP(4, duC, duD, unB, 2, 4)
        // gg7
        LOADN(unB)
        STEP(0, duD, duC, unA, 3, 4) STEP(1, duD, duC, unA, 4, 4) STEP(2, duD, duC, unA, 5, 4)
        STEP(3, duD, duC, unA, 6, 4) STEP(4, duD, duC, unA, 7, 4) STORE(4)

        spf += 80;
    }

    // ---- tail: t = 1005..1018 (14 steps), per-step stores from n==0 lanes ----
    // state: unA holds rows 1005..1013, unB holds 1010..1018, upn -> 1015
    float* tpf = outf + 1005 * 2 + kk;
#define TSTEP(S, UN, K)                                                      \
    {                                                                        \
        float zh_ = fmaf(wh[0], h[(S) % 5], seed);                           \
        zh_ = fmaf(wh[1], h[((S) + 1) % 5], zh_);                            \
        zh_ = fmaf(wh[2], h[((S) + 2) % 5], zh_);                            \
        zh_ = fmaf(wh[3], h[((S) + 3) % 5], zh_);                            \
        zh_ = fmaf(wh[4], h[((S) + 4) % 5], zh_);                            \
        float d_ = wu[0] * UN[S];                                            \
        d_ = fmaf(wu[1], UN[(S) + 1], d_);                                   \
        d_ = fmaf(wu[2], UN[(S) + 2], d_);                                   \
        d_ = fmaf(wu[3], UN[(S) + 3], d_);                                   \
        d_ = fmaf(wu[4], UN[(S) + 4], d_);                                   \
        float zp_ = d_ + zh_;                                                \
        float z_  = comb16(zp_);                                             \
        float r_ = __builtin_amdgcn_rcpf(fast_exp2(z_) + 1.0f);              \
        float y_ = sum8(fmaf(c1, r_, c0));                                   \
        if (n == 0) tpf[2 * (K)] = y_;                                       \
        h[(S) % 5] = y_;                                                     \
    }

    TSTEP(0, unA, 0) TSTEP(1, unA, 1) TSTEP(2, unA, 2) TSTEP(3, unA, 3) TSTEP(4, unA, 4)
    LOADN(unA)   // t0=1015, rows 1015..1023 (in bounds)
    TSTEP(0, unB, 5) TSTEP(1, unB, 6) TSTEP(2, unB, 7) TSTEP(3, unB, 8) TSTEP(4, unB, 9)
    TSTEP(0, unA, 10) TSTEP(1, unA, 11) TSTEP(2, unA, 12) TSTEP(3, unA, 13)

#undef TSTEP
#undef STORE
#undef STEP
#undef LOADN
}

extern "C" void kernel_launch(void* const* d_in, const int* in_sizes, int n_in,
                              void* d_out, int out_size, void* d_ws, size_t ws_size,
                              hipStream_t stream) {
    const float* traj = (const float*)d_in[0];
    const float* W1   = (const float*)d_in[1];
    const float* b1   = (const float*)d_in[2];
    const float* W2   = (const float*)d_in[3];
    const float* b2   = (const float*)d_in[4];
    float* out = (float*)d_out;

    // 16 lanes/element (split-K halves), 4 elements/wave
    // -> 2048 single-wave blocks = 2 waves/SIMD chip-wide (the TLP that hides the chain)
    const int grid = 8192 / 4;
    MLP_or_nextstep_kernel<<<grid, 64, 0, stream>>>(traj, W1, b1, W2, b2, out);
}